// Round 6
// baseline (897.465 us; speedup 1.0000x reference)
//
#include <hip/hip_runtime.h>
#include <hip/hip_fp16.h>

#define NN 100000
#define NE 1600000
#define IND 64
#define HID 128
#define NCLS 16
#define GEMMB (NN / 16)   // 6250
#define RBLK 50
#define BK 98             // buckets (1024 nodes each)
#define BW 1024           // nodes per bucket
#define EPB 2048          // edges per block in bucket hist/place
#define NBG ((NE + EPB - 1) / EPB)   // 782 blocks per graph

// ---------------------------------------------------------------------------
// type-pun helpers
__device__ __forceinline__ __half2 as_h2(unsigned u) {
    union { unsigned u; __half2 h; } c; c.u = u; return c.h;
}
__device__ __forceinline__ unsigned as_u32(__half2 h) {
    union { unsigned u; __half2 h; } c; c.h = h; return c.u;
}

// ---------------------------------------------------------------------------
// fp32 -> f16 table conversion (8 elems / thread)
__global__ void conv16_kernel(const float4* __restrict__ x, uint4* __restrict__ o, int n8) {
    int i = blockIdx.x * blockDim.x + threadIdx.x;
    if (i >= n8) return;
    float4 a = x[2 * i], b = x[2 * i + 1];
    uint4 w;
    w.x = as_u32(__floats2half2_rn(a.x, a.y));
    w.y = as_u32(__floats2half2_rn(a.z, a.w));
    w.z = as_u32(__floats2half2_rn(b.x, b.y));
    w.w = as_u32(__floats2half2_rn(b.z, b.w));
    o[i] = w;
}

// ---------------------------------------------------------------------------
// bucket histogram (both graphs)
__global__ void bucket_hist(const int* __restrict__ d0, const int* __restrict__ d1,
                            int* __restrict__ bcnt) {
    __shared__ int h[BK];
    const int bi = blockIdx.x;
    const int g = bi >= NBG;
    const int* dst = g ? d1 : d0;
    const int base = (g ? bi - NBG : bi) * EPB;
    for (int i = threadIdx.x; i < BK; i += 256) h[i] = 0;
    __syncthreads();
    for (int j = 0; j < EPB; j += 256) {
        int e = base + j + threadIdx.x;
        if (e < NE) atomicAdd(&h[dst[e] >> 10], 1);
    }
    __syncthreads();
    for (int i = threadIdx.x; i < BK; i += 256)
        if (h[i]) atomicAdd(&bcnt[g * BK + i], h[i]);
}

// ---------------------------------------------------------------------------
__global__ void bucket_scan(const int* __restrict__ bcnt, int* __restrict__ bbase,
                            int* __restrict__ bcur) {
    int t = threadIdx.x;
    if (t < 2) {
        int run = 0;
        for (int i = 0; i < BK; i++) {
            bbase[t * (BK + 1) + i] = run;
            bcur[t * BK + i] = run;
            run += bcnt[t * BK + i];
        }
        bbase[t * (BK + 1) + BK] = run;
    }
}

// ---------------------------------------------------------------------------
// partition edges into bucket regions: src | (dst&1023)<<17
__global__ void bucket_place(const int* __restrict__ s0, const int* __restrict__ d0,
                             const int* __restrict__ s1, const int* __restrict__ d1,
                             int* __restrict__ bcur,
                             unsigned* __restrict__ p0, unsigned* __restrict__ p1) {
    __shared__ int h[BK], hb[BK];
    const int bi = blockIdx.x;
    const int g = bi >= NBG;
    const int* src = g ? s1 : s0;
    const int* dst = g ? d1 : d0;
    unsigned* pairs = g ? p1 : p0;
    const int base = (g ? bi - NBG : bi) * EPB;
    for (int i = threadIdx.x; i < BK; i += 256) h[i] = 0;
    __syncthreads();
    for (int j = 0; j < EPB; j += 256) {
        int e = base + j + threadIdx.x;
        if (e < NE) atomicAdd(&h[dst[e] >> 10], 1);
    }
    __syncthreads();
    for (int i = threadIdx.x; i < BK; i += 256) {
        hb[i] = h[i] ? atomicAdd(&bcur[g * BK + i], h[i]) : 0;
        h[i] = 0;
    }
    __syncthreads();
    for (int j = 0; j < EPB; j += 256) {
        int e = base + j + threadIdx.x;
        if (e < NE) {
            int d = dst[e];
            int b = d >> 10;
            int slot = atomicAdd(&h[b], 1);
            pairs[hb[b] + slot] = (unsigned)src[e] | ((unsigned)(d & 1023) << 17);
        }
    }
}

// ---------------------------------------------------------------------------
// one block per bucket: LDS hist + scan, write rowend + ssrc
__global__ __launch_bounds__(256) void bucket_final(
    const unsigned* __restrict__ p0, const unsigned* __restrict__ p1,
    const int* __restrict__ bbase,
    int* __restrict__ row0, int* __restrict__ row1,
    int* __restrict__ ss0, int* __restrict__ ss1) {
    __shared__ int cnt[BW];
    __shared__ int ex[BW];
    __shared__ int aux[256];
    const int bi = blockIdx.x;
    const int g = bi >= BK;
    const int b = g ? bi - BK : bi;
    const unsigned* pairs = g ? p1 : p0;
    int* rowend = g ? row1 : row0;
    int* ssrc = g ? ss1 : ss0;
    const int ebase = bbase[g * (BK + 1) + b];
    const int eend = bbase[g * (BK + 1) + b + 1];
    const int tid = threadIdx.x;

    for (int i = tid; i < BW; i += 256) cnt[i] = 0;
    __syncthreads();
    for (int e = ebase + tid; e < eend; e += 256)
        atomicAdd(&cnt[pairs[e] >> 17], 1);
    __syncthreads();

    int c0 = cnt[4 * tid], c1 = cnt[4 * tid + 1], c2 = cnt[4 * tid + 2], c3 = cnt[4 * tid + 3];
    aux[tid] = c0 + c1 + c2 + c3;
    __syncthreads();
    for (int off = 1; off < 256; off <<= 1) {
        int v = (tid >= off) ? aux[tid - off] : 0;
        __syncthreads();
        aux[tid] += v;
        __syncthreads();
    }
    int excl = tid ? aux[tid - 1] : 0;
    ex[4 * tid] = excl;
    ex[4 * tid + 1] = excl + c0;
    ex[4 * tid + 2] = excl + c0 + c1;
    ex[4 * tid + 3] = excl + c0 + c1 + c2;

    const int nodebase = b * BW + 4 * tid;
    if (nodebase + 0 < NN) rowend[nodebase + 0] = ebase + excl + c0;
    if (nodebase + 1 < NN) rowend[nodebase + 1] = ebase + excl + c0 + c1;
    if (nodebase + 2 < NN) rowend[nodebase + 2] = ebase + excl + c0 + c1 + c2;
    if (nodebase + 3 < NN) rowend[nodebase + 3] = ebase + excl + c0 + c1 + c2 + c3;
    __syncthreads();

    for (int e = ebase + tid; e < eend; e += 256) {
        unsigned pk = pairs[e];
        int dl = pk >> 17;
        int pos = ebase + atomicAdd(&ex[dl], 1);
        ssrc[pos] = (int)(pk & 0x1FFFFu);
    }
}

// ---------------------------------------------------------------------------
// Fused SAGE layer. f16 gather tables, v_pk_add_f16 accumulation.
// x16: f16 table [NN][KS] (KS/8 uint4 per row). Layer1 self from fp32 feats;
// layer2 self from the h1 f16 table.
template<int KS, bool REDUCE>
__global__ __launch_bounds__(256) void sage_fused(
    const float* __restrict__ xf, const uint4* __restrict__ x16,
    const int* __restrict__ ssrc, const int* __restrict__ rowend,
    const float* __restrict__ Ws, const float* __restrict__ Wn,
    float* __restrict__ outR, unsigned* __restrict__ outH) {
    __shared__ float xms[16][2 * KS + 4];
    __shared__ float part[4][128];

    const int tid = threadIdx.x;
    const int n0 = blockIdx.x * 16;
    const int RW = KS / 8;  // uint4 per f16 row

    // ---- self staging ----
    {
        int node = tid / 16, c = tid % 16;
        if constexpr (KS == IND) {
            float4 v = ((const float4*)xf)[(size_t)(n0 + node) * 16 + c];
            *(float4*)&xms[node][c * 4] = v;
        } else {
            uint4 u = x16[(size_t)(n0 + node) * RW + c];
            float2 f0 = __half22float2(as_h2(u.x));
            float2 f1 = __half22float2(as_h2(u.y));
            float2 f2 = __half22float2(as_h2(u.z));
            float2 f3 = __half22float2(as_h2(u.w));
            *(float4*)&xms[node][c * 8] = make_float4(f0.x, f0.y, f1.x, f1.y);
            *(float4*)&xms[node][c * 8 + 4] = make_float4(f2.x, f2.y, f3.x, f3.y);
        }
    }

    // ---- neighbor mean aggregation (f16 gather, pk_add_f16 acc) ----
    {
        const int nb = tid >> 4;
        const int n = n0 + nb;
        const int start = (n == 0) ? 0 : rowend[n - 1];
        const int end = rowend[n];
        __half2 hacc[4];
        hacc[0] = hacc[1] = hacc[2] = hacc[3] = __float2half2_rn(0.0f);

        if constexpr (KS == HID) {
            // 16 lanes/node (full row), single chain, unroll x4
            const int l = tid & 15;
            const uint4* base = x16 + l;
            int e = start;
            for (; e + 4 <= end; e += 4) {
                int i0 = ssrc[e], i1 = ssrc[e + 1], i2 = ssrc[e + 2], i3 = ssrc[e + 3];
                uint4 v0 = base[(size_t)i0 * RW];
                uint4 v1 = base[(size_t)i1 * RW];
                uint4 v2 = base[(size_t)i2 * RW];
                uint4 v3 = base[(size_t)i3 * RW];
                hacc[0] = __hadd2(hacc[0], as_h2(v0.x)); hacc[1] = __hadd2(hacc[1], as_h2(v0.y));
                hacc[2] = __hadd2(hacc[2], as_h2(v0.z)); hacc[3] = __hadd2(hacc[3], as_h2(v0.w));
                hacc[0] = __hadd2(hacc[0], as_h2(v1.x)); hacc[1] = __hadd2(hacc[1], as_h2(v1.y));
                hacc[2] = __hadd2(hacc[2], as_h2(v1.z)); hacc[3] = __hadd2(hacc[3], as_h2(v1.w));
                hacc[0] = __hadd2(hacc[0], as_h2(v2.x)); hacc[1] = __hadd2(hacc[1], as_h2(v2.y));
                hacc[2] = __hadd2(hacc[2], as_h2(v2.z)); hacc[3] = __hadd2(hacc[3], as_h2(v2.w));
                hacc[0] = __hadd2(hacc[0], as_h2(v3.x)); hacc[1] = __hadd2(hacc[1], as_h2(v3.y));
                hacc[2] = __hadd2(hacc[2], as_h2(v3.z)); hacc[3] = __hadd2(hacc[3], as_h2(v3.w));
            }
            for (; e < end; e++) {
                uint4 v = base[(size_t)ssrc[e] * RW];
                hacc[0] = __hadd2(hacc[0], as_h2(v.x)); hacc[1] = __hadd2(hacc[1], as_h2(v.y));
                hacc[2] = __hadd2(hacc[2], as_h2(v.z)); hacc[3] = __hadd2(hacc[3], as_h2(v.w));
            }
            float iv = 1.0f / fmaxf((float)(end - start), 1.0f);
            float2 f0 = __half22float2(hacc[0]);
            float2 f1 = __half22float2(hacc[1]);
            float2 f2 = __half22float2(hacc[2]);
            float2 f3 = __half22float2(hacc[3]);
            *(float4*)&xms[nb][KS + l * 8] =
                make_float4(f0.x * iv, f0.y * iv, f1.x * iv, f1.y * iv);
            *(float4*)&xms[nb][KS + l * 8 + 4] =
                make_float4(f2.x * iv, f2.y * iv, f3.x * iv, f3.y * iv);
        } else {
            // 8 lanes/node x 2 chains (even/odd edges), unroll x2 per chain
            const int sub = tid & 15;
            const int l = sub & 7;
            const int h = sub >> 3;
            const uint4* base = x16 + l;
            int e = start + h;
            for (; e + 2 < end; e += 4) {
                int i0 = ssrc[e], i1 = ssrc[e + 2];
                uint4 v0 = base[(size_t)i0 * RW];
                uint4 v1 = base[(size_t)i1 * RW];
                hacc[0] = __hadd2(hacc[0], as_h2(v0.x)); hacc[1] = __hadd2(hacc[1], as_h2(v0.y));
                hacc[2] = __hadd2(hacc[2], as_h2(v0.z)); hacc[3] = __hadd2(hacc[3], as_h2(v0.w));
                hacc[0] = __hadd2(hacc[0], as_h2(v1.x)); hacc[1] = __hadd2(hacc[1], as_h2(v1.y));
                hacc[2] = __hadd2(hacc[2], as_h2(v1.z)); hacc[3] = __hadd2(hacc[3], as_h2(v1.w));
            }
            if (e < end) {
                uint4 v = base[(size_t)ssrc[e] * RW];
                hacc[0] = __hadd2(hacc[0], as_h2(v.x)); hacc[1] = __hadd2(hacc[1], as_h2(v.y));
                hacc[2] = __hadd2(hacc[2], as_h2(v.z)); hacc[3] = __hadd2(hacc[3], as_h2(v.w));
            }
#pragma unroll
            for (int j = 0; j < 4; j++) {
                int t = __shfl_xor(as_u32(hacc[j]), 8);
                hacc[j] = __hadd2(hacc[j], as_h2((unsigned)t));
            }
            if (h == 0) {
                float iv = 1.0f / fmaxf((float)(end - start), 1.0f);
                float2 f0 = __half22float2(hacc[0]);
                float2 f1 = __half22float2(hacc[1]);
                float2 f2 = __half22float2(hacc[2]);
                float2 f3 = __half22float2(hacc[3]);
                *(float4*)&xms[nb][KS + l * 8] =
                    make_float4(f0.x * iv, f0.y * iv, f1.x * iv, f1.y * iv);
                *(float4*)&xms[nb][KS + l * 8 + 4] =
                    make_float4(f2.x * iv, f2.y * iv, f3.x * iv, f3.y * iv);
            }
        }
    }
    __syncthreads();

    // ---- GEMM: out = relu([xs|ms] @ [Ws;Wn]) ----
    const int p = tid % 64;
    const int q = tid / 64;
    float a00 = 0, a01 = 0, a10 = 0, a11 = 0, a20 = 0, a21 = 0, a30 = 0, a31 = 0;

#pragma unroll
    for (int seg = 0; seg < 2; seg++) {
        const float* __restrict__ W = seg ? Wn : Ws;
        const int koff = seg * KS;
#pragma unroll 2
        for (int k = 0; k < KS; k += 4) {
            const float* Wk = W + (size_t)k * HID + 2 * p;
            float2 w0 = *(const float2*)(Wk);
            float2 w1 = *(const float2*)(Wk + HID);
            float2 w2 = *(const float2*)(Wk + 2 * HID);
            float2 w3 = *(const float2*)(Wk + 3 * HID);
            float4 v0 = *(const float4*)&xms[4 * q + 0][koff + k];
            float4 v1 = *(const float4*)&xms[4 * q + 1][koff + k];
            float4 v2 = *(const float4*)&xms[4 * q + 2][koff + k];
            float4 v3 = *(const float4*)&xms[4 * q + 3][koff + k];
            a00 += v0.x * w0.x + v0.y * w1.x + v0.z * w2.x + v0.w * w3.x;
            a01 += v0.x * w0.y + v0.y * w1.y + v0.z * w2.y + v0.w * w3.y;
            a10 += v1.x * w0.x + v1.y * w1.x + v1.z * w2.x + v1.w * w3.x;
            a11 += v1.x * w0.y + v1.y * w1.y + v1.z * w2.y + v1.w * w3.y;
            a20 += v2.x * w0.x + v2.y * w1.x + v2.z * w2.x + v2.w * w3.x;
            a21 += v2.x * w0.y + v2.y * w1.y + v2.z * w2.y + v2.w * w3.y;
            a30 += v3.x * w0.x + v3.y * w1.x + v3.z * w2.x + v3.w * w3.x;
            a31 += v3.x * w0.y + v3.y * w1.y + v3.z * w2.y + v3.w * w3.y;
        }
    }

    if constexpr (!REDUCE) {
        float r0, r1;
        r0 = fmaxf(a00, 0.f); r1 = fmaxf(a01, 0.f);
        outH[(size_t)(n0 + 4 * q + 0) * 64 + p] = as_u32(__floats2half2_rn(r0, r1));
        r0 = fmaxf(a10, 0.f); r1 = fmaxf(a11, 0.f);
        outH[(size_t)(n0 + 4 * q + 1) * 64 + p] = as_u32(__floats2half2_rn(r0, r1));
        r0 = fmaxf(a20, 0.f); r1 = fmaxf(a21, 0.f);
        outH[(size_t)(n0 + 4 * q + 2) * 64 + p] = as_u32(__floats2half2_rn(r0, r1));
        r0 = fmaxf(a30, 0.f); r1 = fmaxf(a31, 0.f);
        outH[(size_t)(n0 + 4 * q + 3) * 64 + p] = as_u32(__floats2half2_rn(r0, r1));
    } else {
        float s0 = fmaxf(a00, 0.f) + fmaxf(a10, 0.f) + fmaxf(a20, 0.f) + fmaxf(a30, 0.f);
        float s1 = fmaxf(a01, 0.f) + fmaxf(a11, 0.f) + fmaxf(a21, 0.f) + fmaxf(a31, 0.f);
        *(float2*)&part[q][2 * p] = make_float2(s0, s1);
        __syncthreads();
        if (tid < 128) {
            float s = part[0][tid] + part[1][tid] + part[2][tid] + part[3][tid];
            outR[(size_t)blockIdx.x * 128 + tid] = s;
        }
    }
}

// ---------------------------------------------------------------------------
__global__ void reduce1_kernel(const float* __restrict__ p0, const float* __restrict__ p1,
                               float* __restrict__ p2) {
    const int bb = blockIdx.x;
    const int tid = threadIdx.x;
    const int g = tid >> 7;
    const int col = tid & 127;
    const float* p = g ? p1 : p0;
    const int per = GEMMB / RBLK;
    float s = 0.0f;
    for (int r = 0; r < per; r++) s += p[(size_t)(bb * per + r) * 128 + col];
    p2[(size_t)bb * 256 + tid] = s;
}

__global__ void final_kernel(const float* __restrict__ p2,
                             const float* __restrict__ Wlin1,
                             const float* __restrict__ Wlin2,
                             float* __restrict__ out) {
    __shared__ float rep[2][HID];
    __shared__ float sg[32];
    const int tid = threadIdx.x;
    float s = 0.0f;
    for (int r = 0; r < RBLK; r++) s += p2[r * 256 + tid];
    rep[tid >> 7][tid & 127] = s * (1.0f / (float)NN);
    __syncthreads();
    if (tid < 32) {
        const int g = tid / 16;
        const int c = tid % 16;
        const float* W = g ? Wlin2 : Wlin1;
        float a = 0.0f;
        for (int k = 0; k < HID; k++) a += rep[g][k] * W[k * NCLS + c];
        sg[tid] = 1.0f / (1.0f + expf(-a));
    }
    __syncthreads();
    if (tid < 16) out[tid] = 0.5f * (sg[tid] + sg[16 + tid]);
}

// ---------------------------------------------------------------------------
extern "C" void kernel_launch(void* const* d_in, const int* in_sizes, int n_in,
                              void* d_out, int out_size, void* d_ws, size_t ws_size,
                              hipStream_t stream) {
    const float* feats = (const float*)d_in[0];
    const int* srcp[2] = {(const int*)d_in[1], (const int*)d_in[3]};
    const int* dstp[2] = {(const int*)d_in[2], (const int*)d_in[4]};
    const float* Ws1[2] = {(const float*)d_in[5], (const float*)d_in[10]};
    const float* Wn1[2] = {(const float*)d_in[6], (const float*)d_in[11]};
    const float* Ws2[2] = {(const float*)d_in[7], (const float*)d_in[12]};
    const float* Wn2[2] = {(const float*)d_in[8], (const float*)d_in[13]};
    const float* Wlin[2] = {(const float*)d_in[9], (const float*)d_in[14]};

    // workspace layout (~90 MB), 16B-aligned sections
    char* w = (char*)d_ws;
    uint4* fb16 = (uint4*)w;        w += (size_t)NN * IND * 2;      // feats f16
    uint4* h1h = (uint4*)w;         w += (size_t)NN * HID * 2;      // h1 f16
    float* part0 = (float*)w;       w += (size_t)GEMMB * 128 * 4;
    float* part1 = (float*)w;       w += (size_t)GEMMB * 128 * 4;
    float* p2 = (float*)w;          w += (size_t)RBLK * 256 * 4;
    unsigned* pr0 = (unsigned*)w;   w += (size_t)NE * 4;
    unsigned* pr1 = (unsigned*)w;   w += (size_t)NE * 4;
    int* ss0 = (int*)w;             w += (size_t)NE * 4;
    int* ss1 = (int*)w;             w += (size_t)NE * 4;
    int* row0 = (int*)w;            w += (size_t)NN * 4;
    int* row1 = (int*)w;            w += (size_t)NN * 4;
    int* bcnt = (int*)w;            w += 2 * BK * 4;
    int* bbase = (int*)w;           w += 2 * (BK + 1) * 4;
    int* bcur = (int*)w;            w += 2 * BK * 4;

    // feats -> f16 table
    conv16_kernel<<<(NN * IND / 8 + 255) / 256, 256, 0, stream>>>(
        (const float4*)feats, fb16, NN * IND / 8);

    // bucketed CSR build, both graphs
    (void)hipMemsetAsync(bcnt, 0, 2 * BK * 4, stream);
    bucket_hist<<<2 * NBG, 256, 0, stream>>>(dstp[0], dstp[1], bcnt);
    bucket_scan<<<1, 64, 0, stream>>>(bcnt, bbase, bcur);
    bucket_place<<<2 * NBG, 256, 0, stream>>>(srcp[0], dstp[0], srcp[1], dstp[1],
                                              bcur, pr0, pr1);
    bucket_final<<<2 * BK, 256, 0, stream>>>(pr0, pr1, bbase, row0, row1, ss0, ss1);

    const int* ssg[2] = {ss0, ss1};
    const int* rowg[2] = {row0, row1};
    float* partG[2] = {part0, part1};

    for (int g = 0; g < 2; g++) {
        sage_fused<IND, false><<<GEMMB, 256, 0, stream>>>(
            feats, fb16, ssg[g], rowg[g], Ws1[g], Wn1[g], nullptr, (unsigned*)h1h);
        sage_fused<HID, true><<<GEMMB, 256, 0, stream>>>(
            nullptr, h1h, ssg[g], rowg[g], Ws2[g], Wn2[g], partG[g], nullptr);
    }

    reduce1_kernel<<<RBLK, 256, 0, stream>>>(part0, part1, p2);
    final_kernel<<<1, 256, 0, stream>>>(p2, Wlin[0], Wlin[1], (float*)d_out);
}

// Round 7
// 886.112 us; speedup vs baseline: 1.0128x; 1.0128x over previous
//
#include <hip/hip_runtime.h>
#include <hip/hip_fp16.h>

#define NN 100000
#define NE 1600000
#define IND 64
#define HID 128
#define NCLS 16
#define GEMMB (NN / 16)   // 6250
#define RBLK 50
#define BK 98             // buckets (1024 nodes each)
#define BW 1024           // nodes per bucket
#define EPB 2048          // edges per block in bucket hist/place
#define NBG ((NE + EPB - 1) / EPB)   // 782 blocks per graph

// ---------------------------------------------------------------------------
// type-pun helpers
__device__ __forceinline__ __half2 as_h2(unsigned u) {
    union { unsigned u; __half2 h; } c; c.u = u; return c.h;
}
__device__ __forceinline__ unsigned as_u32(__half2 h) {
    union { unsigned u; __half2 h; } c; c.h = h; return c.u;
}

// ---------------------------------------------------------------------------
// fp32 -> f16 table conversion (8 elems / thread)
__global__ void conv16_kernel(const float4* __restrict__ x, uint4* __restrict__ o, int n8) {
    int i = blockIdx.x * blockDim.x + threadIdx.x;
    if (i >= n8) return;
    float4 a = x[2 * i], b = x[2 * i + 1];
    uint4 w;
    w.x = as_u32(__floats2half2_rn(a.x, a.y));
    w.y = as_u32(__floats2half2_rn(a.z, a.w));
    w.z = as_u32(__floats2half2_rn(b.x, b.y));
    w.w = as_u32(__floats2half2_rn(b.z, b.w));
    o[i] = w;
}

// ---------------------------------------------------------------------------
// bucket histogram (both graphs)
__global__ void bucket_hist(const int* __restrict__ d0, const int* __restrict__ d1,
                            int* __restrict__ bcnt) {
    __shared__ int h[BK];
    const int bi = blockIdx.x;
    const int g = bi >= NBG;
    const int* dst = g ? d1 : d0;
    const int base = (g ? bi - NBG : bi) * EPB;
    for (int i = threadIdx.x; i < BK; i += 256) h[i] = 0;
    __syncthreads();
    for (int j = 0; j < EPB; j += 256) {
        int e = base + j + threadIdx.x;
        if (e < NE) atomicAdd(&h[dst[e] >> 10], 1);
    }
    __syncthreads();
    for (int i = threadIdx.x; i < BK; i += 256)
        if (h[i]) atomicAdd(&bcnt[g * BK + i], h[i]);
}

// ---------------------------------------------------------------------------
__global__ void bucket_scan(const int* __restrict__ bcnt, int* __restrict__ bbase,
                            int* __restrict__ bcur) {
    int t = threadIdx.x;
    if (t < 2) {
        int run = 0;
        for (int i = 0; i < BK; i++) {
            bbase[t * (BK + 1) + i] = run;
            bcur[t * BK + i] = run;
            run += bcnt[t * BK + i];
        }
        bbase[t * (BK + 1) + BK] = run;
    }
}

// ---------------------------------------------------------------------------
// partition edges into bucket regions: src | (dst&1023)<<17
__global__ void bucket_place(const int* __restrict__ s0, const int* __restrict__ d0,
                             const int* __restrict__ s1, const int* __restrict__ d1,
                             int* __restrict__ bcur,
                             unsigned* __restrict__ p0, unsigned* __restrict__ p1) {
    __shared__ int h[BK], hb[BK];
    const int bi = blockIdx.x;
    const int g = bi >= NBG;
    const int* src = g ? s1 : s0;
    const int* dst = g ? d1 : d0;
    unsigned* pairs = g ? p1 : p0;
    const int base = (g ? bi - NBG : bi) * EPB;
    for (int i = threadIdx.x; i < BK; i += 256) h[i] = 0;
    __syncthreads();
    for (int j = 0; j < EPB; j += 256) {
        int e = base + j + threadIdx.x;
        if (e < NE) atomicAdd(&h[dst[e] >> 10], 1);
    }
    __syncthreads();
    for (int i = threadIdx.x; i < BK; i += 256) {
        hb[i] = h[i] ? atomicAdd(&bcur[g * BK + i], h[i]) : 0;
        h[i] = 0;
    }
    __syncthreads();
    for (int j = 0; j < EPB; j += 256) {
        int e = base + j + threadIdx.x;
        if (e < NE) {
            int d = dst[e];
            int b = d >> 10;
            int slot = atomicAdd(&h[b], 1);
            pairs[hb[b] + slot] = (unsigned)src[e] | ((unsigned)(d & 1023) << 17);
        }
    }
}

// ---------------------------------------------------------------------------
// one block per bucket: LDS hist + scan, write rowend + ssrc
__global__ __launch_bounds__(256) void bucket_final(
    const unsigned* __restrict__ p0, const unsigned* __restrict__ p1,
    const int* __restrict__ bbase,
    int* __restrict__ row0, int* __restrict__ row1,
    int* __restrict__ ss0, int* __restrict__ ss1) {
    __shared__ int cnt[BW];
    __shared__ int ex[BW];
    __shared__ int aux[256];
    const int bi = blockIdx.x;
    const int g = bi >= BK;
    const int b = g ? bi - BK : bi;
    const unsigned* pairs = g ? p1 : p0;
    int* rowend = g ? row1 : row0;
    int* ssrc = g ? ss1 : ss0;
    const int ebase = bbase[g * (BK + 1) + b];
    const int eend = bbase[g * (BK + 1) + b + 1];
    const int tid = threadIdx.x;

    for (int i = tid; i < BW; i += 256) cnt[i] = 0;
    __syncthreads();
    for (int e = ebase + tid; e < eend; e += 256)
        atomicAdd(&cnt[pairs[e] >> 17], 1);
    __syncthreads();

    int c0 = cnt[4 * tid], c1 = cnt[4 * tid + 1], c2 = cnt[4 * tid + 2], c3 = cnt[4 * tid + 3];
    aux[tid] = c0 + c1 + c2 + c3;
    __syncthreads();
    for (int off = 1; off < 256; off <<= 1) {
        int v = (tid >= off) ? aux[tid - off] : 0;
        __syncthreads();
        aux[tid] += v;
        __syncthreads();
    }
    int excl = tid ? aux[tid - 1] : 0;
    ex[4 * tid] = excl;
    ex[4 * tid + 1] = excl + c0;
    ex[4 * tid + 2] = excl + c0 + c1;
    ex[4 * tid + 3] = excl + c0 + c1 + c2;

    const int nodebase = b * BW + 4 * tid;
    if (nodebase + 0 < NN) rowend[nodebase + 0] = ebase + excl + c0;
    if (nodebase + 1 < NN) rowend[nodebase + 1] = ebase + excl + c0 + c1;
    if (nodebase + 2 < NN) rowend[nodebase + 2] = ebase + excl + c0 + c1 + c2;
    if (nodebase + 3 < NN) rowend[nodebase + 3] = ebase + excl + c0 + c1 + c2 + c3;
    __syncthreads();

    for (int e = ebase + tid; e < eend; e += 256) {
        unsigned pk = pairs[e];
        int dl = pk >> 17;
        int pos = ebase + atomicAdd(&ex[dl], 1);
        ssrc[pos] = (int)(pk & 0x1FFFFu);
    }
}

// ---------------------------------------------------------------------------
// Fused SAGE layer. f16 gather tables, v_pk_add_f16 accumulation, deep MLP.
template<int KS, bool REDUCE>
__global__ __launch_bounds__(256) void sage_fused(
    const float* __restrict__ xf, const uint4* __restrict__ x16,
    const int* __restrict__ ssrc, const int* __restrict__ rowend,
    const float* __restrict__ Ws, const float* __restrict__ Wn,
    float* __restrict__ outR, unsigned* __restrict__ outH) {
    __shared__ float xms[16][2 * KS + 4];
    __shared__ float part[4][128];

    const int tid = threadIdx.x;
    const int n0 = blockIdx.x * 16;
    const int RW = KS / 8;  // uint4 per f16 row

    // ---- self staging ----
    {
        int node = tid / 16, c = tid % 16;
        if constexpr (KS == IND) {
            float4 v = ((const float4*)xf)[(size_t)(n0 + node) * 16 + c];
            *(float4*)&xms[node][c * 4] = v;
        } else {
            uint4 u = x16[(size_t)(n0 + node) * RW + c];
            float2 f0 = __half22float2(as_h2(u.x));
            float2 f1 = __half22float2(as_h2(u.y));
            float2 f2 = __half22float2(as_h2(u.z));
            float2 f3 = __half22float2(as_h2(u.w));
            *(float4*)&xms[node][c * 8] = make_float4(f0.x, f0.y, f1.x, f1.y);
            *(float4*)&xms[node][c * 8 + 4] = make_float4(f2.x, f2.y, f3.x, f3.y);
        }
    }

    // ---- neighbor mean aggregation: each lane owns 16 cols (2 uint4/edge),
    //      multiple chains per node for MLP, combined via shfl_xor ----
    {
        const int nb = tid >> 4;
        const int n = n0 + nb;
        const int start = (n == 0) ? 0 : rowend[n - 1];
        const int end = rowend[n];
        __half2 hacc[8];
#pragma unroll
        for (int j = 0; j < 8; j++) hacc[j] = __float2half2_rn(0.0f);

        if constexpr (KS == HID) {
            // 8 lanes/node x 2 chains; 2 loads/edge/lane; unroll 4 edges/chain
            const int sub = tid & 15;
            const int l = sub & 7;          // cols 16l..16l+16
            const int h = sub >> 3;         // chain
            const uint4* base = x16 + 2 * l;
            int e = start + h;
            for (; e + 6 < end; e += 8) {   // edges e, e+2, e+4, e+6
                int i0 = ssrc[e], i1 = ssrc[e + 2], i2 = ssrc[e + 4], i3 = ssrc[e + 6];
                uint4 a0 = base[(size_t)i0 * 16], b0 = base[(size_t)i0 * 16 + 1];
                uint4 a1 = base[(size_t)i1 * 16], b1 = base[(size_t)i1 * 16 + 1];
                uint4 a2 = base[(size_t)i2 * 16], b2 = base[(size_t)i2 * 16 + 1];
                uint4 a3 = base[(size_t)i3 * 16], b3 = base[(size_t)i3 * 16 + 1];
                hacc[0] = __hadd2(hacc[0], as_h2(a0.x)); hacc[1] = __hadd2(hacc[1], as_h2(a0.y));
                hacc[2] = __hadd2(hacc[2], as_h2(a0.z)); hacc[3] = __hadd2(hacc[3], as_h2(a0.w));
                hacc[4] = __hadd2(hacc[4], as_h2(b0.x)); hacc[5] = __hadd2(hacc[5], as_h2(b0.y));
                hacc[6] = __hadd2(hacc[6], as_h2(b0.z)); hacc[7] = __hadd2(hacc[7], as_h2(b0.w));
                hacc[0] = __hadd2(hacc[0], as_h2(a1.x)); hacc[1] = __hadd2(hacc[1], as_h2(a1.y));
                hacc[2] = __hadd2(hacc[2], as_h2(a1.z)); hacc[3] = __hadd2(hacc[3], as_h2(a1.w));
                hacc[4] = __hadd2(hacc[4], as_h2(b1.x)); hacc[5] = __hadd2(hacc[5], as_h2(b1.y));
                hacc[6] = __hadd2(hacc[6], as_h2(b1.z)); hacc[7] = __hadd2(hacc[7], as_h2(b1.w));
                hacc[0] = __hadd2(hacc[0], as_h2(a2.x)); hacc[1] = __hadd2(hacc[1], as_h2(a2.y));
                hacc[2] = __hadd2(hacc[2], as_h2(a2.z)); hacc[3] = __hadd2(hacc[3], as_h2(a2.w));
                hacc[4] = __hadd2(hacc[4], as_h2(b2.x)); hacc[5] = __hadd2(hacc[5], as_h2(b2.y));
                hacc[6] = __hadd2(hacc[6], as_h2(b2.z)); hacc[7] = __hadd2(hacc[7], as_h2(b2.w));
                hacc[0] = __hadd2(hacc[0], as_h2(a3.x)); hacc[1] = __hadd2(hacc[1], as_h2(a3.y));
                hacc[2] = __hadd2(hacc[2], as_h2(a3.z)); hacc[3] = __hadd2(hacc[3], as_h2(a3.w));
                hacc[4] = __hadd2(hacc[4], as_h2(b3.x)); hacc[5] = __hadd2(hacc[5], as_h2(b3.y));
                hacc[6] = __hadd2(hacc[6], as_h2(b3.z)); hacc[7] = __hadd2(hacc[7], as_h2(b3.w));
            }
            for (; e < end; e += 2) {
                int i = ssrc[e];
                uint4 a = base[(size_t)i * 16], b = base[(size_t)i * 16 + 1];
                hacc[0] = __hadd2(hacc[0], as_h2(a.x)); hacc[1] = __hadd2(hacc[1], as_h2(a.y));
                hacc[2] = __hadd2(hacc[2], as_h2(a.z)); hacc[3] = __hadd2(hacc[3], as_h2(a.w));
                hacc[4] = __hadd2(hacc[4], as_h2(b.x)); hacc[5] = __hadd2(hacc[5], as_h2(b.y));
                hacc[6] = __hadd2(hacc[6], as_h2(b.z)); hacc[7] = __hadd2(hacc[7], as_h2(b.w));
            }
#pragma unroll
            for (int j = 0; j < 8; j++) {
                int t = __shfl_xor((int)as_u32(hacc[j]), 8);
                hacc[j] = __hadd2(hacc[j], as_h2((unsigned)t));
            }
            if (h == 0) {
                float iv = 1.0f / fmaxf((float)(end - start), 1.0f);
#pragma unroll
                for (int j = 0; j < 4; j++) {
                    float2 fa = __half22float2(hacc[2 * j]);
                    float2 fb = __half22float2(hacc[2 * j + 1]);
                    *(float4*)&xms[nb][KS + l * 16 + 4 * j] =
                        make_float4(fa.x * iv, fa.y * iv, fb.x * iv, fb.y * iv);
                }
            }
        } else {
            // 4 lanes/node x 4 chains; 2 loads/edge/lane; unroll 2 edges/chain
            const int sub = tid & 15;
            const int l = sub & 3;          // cols 16l..16l+16 (row = 64)
            const int h = sub >> 2;         // chain 0..3
            const uint4* base = x16 + 2 * l;
            int e = start + h;
            for (; e + 4 < end; e += 8) {   // edges e, e+4
                int i0 = ssrc[e], i1 = ssrc[e + 4];
                uint4 a0 = base[(size_t)i0 * 8], b0 = base[(size_t)i0 * 8 + 1];
                uint4 a1 = base[(size_t)i1 * 8], b1 = base[(size_t)i1 * 8 + 1];
                hacc[0] = __hadd2(hacc[0], as_h2(a0.x)); hacc[1] = __hadd2(hacc[1], as_h2(a0.y));
                hacc[2] = __hadd2(hacc[2], as_h2(a0.z)); hacc[3] = __hadd2(hacc[3], as_h2(a0.w));
                hacc[4] = __hadd2(hacc[4], as_h2(b0.x)); hacc[5] = __hadd2(hacc[5], as_h2(b0.y));
                hacc[6] = __hadd2(hacc[6], as_h2(b0.z)); hacc[7] = __hadd2(hacc[7], as_h2(b0.w));
                hacc[0] = __hadd2(hacc[0], as_h2(a1.x)); hacc[1] = __hadd2(hacc[1], as_h2(a1.y));
                hacc[2] = __hadd2(hacc[2], as_h2(a1.z)); hacc[3] = __hadd2(hacc[3], as_h2(a1.w));
                hacc[4] = __hadd2(hacc[4], as_h2(b1.x)); hacc[5] = __hadd2(hacc[5], as_h2(b1.y));
                hacc[6] = __hadd2(hacc[6], as_h2(b1.z)); hacc[7] = __hadd2(hacc[7], as_h2(b1.w));
            }
            for (; e < end; e += 4) {
                int i = ssrc[e];
                uint4 a = base[(size_t)i * 8], b = base[(size_t)i * 8 + 1];
                hacc[0] = __hadd2(hacc[0], as_h2(a.x)); hacc[1] = __hadd2(hacc[1], as_h2(a.y));
                hacc[2] = __hadd2(hacc[2], as_h2(a.z)); hacc[3] = __hadd2(hacc[3], as_h2(a.w));
                hacc[4] = __hadd2(hacc[4], as_h2(b.x)); hacc[5] = __hadd2(hacc[5], as_h2(b.y));
                hacc[6] = __hadd2(hacc[6], as_h2(b.z)); hacc[7] = __hadd2(hacc[7], as_h2(b.w));
            }
#pragma unroll
            for (int j = 0; j < 8; j++) {
                int t = __shfl_xor((int)as_u32(hacc[j]), 4);
                hacc[j] = __hadd2(hacc[j], as_h2((unsigned)t));
            }
#pragma unroll
            for (int j = 0; j < 8; j++) {
                int t = __shfl_xor((int)as_u32(hacc[j]), 8);
                hacc[j] = __hadd2(hacc[j], as_h2((unsigned)t));
            }
            if (h == 0) {
                float iv = 1.0f / fmaxf((float)(end - start), 1.0f);
#pragma unroll
                for (int j = 0; j < 4; j++) {
                    float2 fa = __half22float2(hacc[2 * j]);
                    float2 fb = __half22float2(hacc[2 * j + 1]);
                    *(float4*)&xms[nb][KS + l * 16 + 4 * j] =
                        make_float4(fa.x * iv, fa.y * iv, fb.x * iv, fb.y * iv);
                }
            }
        }
    }
    __syncthreads();

    // ---- GEMM: out = relu([xs|ms] @ [Ws;Wn]) ----
    const int p = tid % 64;
    const int q = tid / 64;
    float a00 = 0, a01 = 0, a10 = 0, a11 = 0, a20 = 0, a21 = 0, a30 = 0, a31 = 0;

#pragma unroll
    for (int seg = 0; seg < 2; seg++) {
        const float* __restrict__ W = seg ? Wn : Ws;
        const int koff = seg * KS;
#pragma unroll 2
        for (int k = 0; k < KS; k += 4) {
            const float* Wk = W + (size_t)k * HID + 2 * p;
            float2 w0 = *(const float2*)(Wk);
            float2 w1 = *(const float2*)(Wk + HID);
            float2 w2 = *(const float2*)(Wk + 2 * HID);
            float2 w3 = *(const float2*)(Wk + 3 * HID);
            float4 v0 = *(const float4*)&xms[4 * q + 0][koff + k];
            float4 v1 = *(const float4*)&xms[4 * q + 1][koff + k];
            float4 v2 = *(const float4*)&xms[4 * q + 2][koff + k];
            float4 v3 = *(const float4*)&xms[4 * q + 3][koff + k];
            a00 += v0.x * w0.x + v0.y * w1.x + v0.z * w2.x + v0.w * w3.x;
            a01 += v0.x * w0.y + v0.y * w1.y + v0.z * w2.y + v0.w * w3.y;
            a10 += v1.x * w0.x + v1.y * w1.x + v1.z * w2.x + v1.w * w3.x;
            a11 += v1.x * w0.y + v1.y * w1.y + v1.z * w2.y + v1.w * w3.y;
            a20 += v2.x * w0.x + v2.y * w1.x + v2.z * w2.x + v2.w * w3.x;
            a21 += v2.x * w0.y + v2.y * w1.y + v2.z * w2.y + v2.w * w3.y;
            a30 += v3.x * w0.x + v3.y * w1.x + v3.z * w2.x + v3.w * w3.x;
            a31 += v3.x * w0.y + v3.y * w1.y + v3.z * w2.y + v3.w * w3.y;
        }
    }

    if constexpr (!REDUCE) {
        float r0, r1;
        r0 = fmaxf(a00, 0.f); r1 = fmaxf(a01, 0.f);
        outH[(size_t)(n0 + 4 * q + 0) * 64 + p] = as_u32(__floats2half2_rn(r0, r1));
        r0 = fmaxf(a10, 0.f); r1 = fmaxf(a11, 0.f);
        outH[(size_t)(n0 + 4 * q + 1) * 64 + p] = as_u32(__floats2half2_rn(r0, r1));
        r0 = fmaxf(a20, 0.f); r1 = fmaxf(a21, 0.f);
        outH[(size_t)(n0 + 4 * q + 2) * 64 + p] = as_u32(__floats2half2_rn(r0, r1));
        r0 = fmaxf(a30, 0.f); r1 = fmaxf(a31, 0.f);
        outH[(size_t)(n0 + 4 * q + 3) * 64 + p] = as_u32(__floats2half2_rn(r0, r1));
    } else {
        float s0 = fmaxf(a00, 0.f) + fmaxf(a10, 0.f) + fmaxf(a20, 0.f) + fmaxf(a30, 0.f);
        float s1 = fmaxf(a01, 0.f) + fmaxf(a11, 0.f) + fmaxf(a21, 0.f) + fmaxf(a31, 0.f);
        *(float2*)&part[q][2 * p] = make_float2(s0, s1);
        __syncthreads();
        if (tid < 128) {
            float s = part[0][tid] + part[1][tid] + part[2][tid] + part[3][tid];
            outR[(size_t)blockIdx.x * 128 + tid] = s;
        }
    }
}

// ---------------------------------------------------------------------------
__global__ void reduce1_kernel(const float* __restrict__ p0, const float* __restrict__ p1,
                               float* __restrict__ p2) {
    const int bb = blockIdx.x;
    const int tid = threadIdx.x;
    const int g = tid >> 7;
    const int col = tid & 127;
    const float* p = g ? p1 : p0;
    const int per = GEMMB / RBLK;
    float s = 0.0f;
    for (int r = 0; r < per; r++) s += p[(size_t)(bb * per + r) * 128 + col];
    p2[(size_t)bb * 256 + tid] = s;
}

__global__ void final_kernel(const float* __restrict__ p2,
                             const float* __restrict__ Wlin1,
                             const float* __restrict__ Wlin2,
                             float* __restrict__ out) {
    __shared__ float rep[2][HID];
    __shared__ float sg[32];
    const int tid = threadIdx.x;
    float s = 0.0f;
    for (int r = 0; r < RBLK; r++) s += p2[r * 256 + tid];
    rep[tid >> 7][tid & 127] = s * (1.0f / (float)NN);
    __syncthreads();
    if (tid < 32) {
        const int g = tid / 16;
        const int c = tid % 16;
        const float* W = g ? Wlin2 : Wlin1;
        float a = 0.0f;
        for (int k = 0; k < HID; k++) a += rep[g][k] * W[k * NCLS + c];
        sg[tid] = 1.0f / (1.0f + expf(-a));
    }
    __syncthreads();
    if (tid < 16) out[tid] = 0.5f * (sg[tid] + sg[16 + tid]);
}

// ---------------------------------------------------------------------------
extern "C" void kernel_launch(void* const* d_in, const int* in_sizes, int n_in,
                              void* d_out, int out_size, void* d_ws, size_t ws_size,
                              hipStream_t stream) {
    const float* feats = (const float*)d_in[0];
    const int* srcp[2] = {(const int*)d_in[1], (const int*)d_in[3]};
    const int* dstp[2] = {(const int*)d_in[2], (const int*)d_in[4]};
    const float* Ws1[2] = {(const float*)d_in[5], (const float*)d_in[10]};
    const float* Wn1[2] = {(const float*)d_in[6], (const float*)d_in[11]};
    const float* Ws2[2] = {(const float*)d_in[7], (const float*)d_in[12]};
    const float* Wn2[2] = {(const float*)d_in[8], (const float*)d_in[13]};
    const float* Wlin[2] = {(const float*)d_in[9], (const float*)d_in[14]};

    // workspace layout (~90 MB), 16B-aligned sections
    char* w = (char*)d_ws;
    uint4* fb16 = (uint4*)w;        w += (size_t)NN * IND * 2;      // feats f16
    uint4* h1h = (uint4*)w;         w += (size_t)NN * HID * 2;      // h1 f16
    float* part0 = (float*)w;       w += (size_t)GEMMB * 128 * 4;
    float* part1 = (float*)w;       w += (size_t)GEMMB * 128 * 4;
    float* p2 = (float*)w;          w += (size_t)RBLK * 256 * 4;
    unsigned* pr0 = (unsigned*)w;   w += (size_t)NE * 4;
    unsigned* pr1 = (unsigned*)w;   w += (size_t)NE * 4;
    int* ss0 = (int*)w;             w += (size_t)NE * 4;
    int* ss1 = (int*)w;             w += (size_t)NE * 4;
    int* row0 = (int*)w;            w += (size_t)NN * 4;
    int* row1 = (int*)w;            w += (size_t)NN * 4;
    int* bcnt = (int*)w;            w += 2 * BK * 4;
    int* bbase = (int*)w;           w += 2 * (BK + 1) * 4;
    int* bcur = (int*)w;            w += 2 * BK * 4;

    // feats -> f16 table
    conv16_kernel<<<(NN * IND / 8 + 255) / 256, 256, 0, stream>>>(
        (const float4*)feats, fb16, NN * IND / 8);

    // bucketed CSR build, both graphs
    (void)hipMemsetAsync(bcnt, 0, 2 * BK * 4, stream);
    bucket_hist<<<2 * NBG, 256, 0, stream>>>(dstp[0], dstp[1], bcnt);
    bucket_scan<<<1, 64, 0, stream>>>(bcnt, bbase, bcur);
    bucket_place<<<2 * NBG, 256, 0, stream>>>(srcp[0], dstp[0], srcp[1], dstp[1],
                                              bcur, pr0, pr1);
    bucket_final<<<2 * BK, 256, 0, stream>>>(pr0, pr1, bbase, row0, row1, ss0, ss1);

    const int* ssg[2] = {ss0, ss1};
    const int* rowg[2] = {row0, row1};
    float* partG[2] = {part0, part1};

    for (int g = 0; g < 2; g++) {
        sage_fused<IND, false><<<GEMMB, 256, 0, stream>>>(
            feats, fb16, ssg[g], rowg[g], Ws1[g], Wn1[g], nullptr, (unsigned*)h1h);
        sage_fused<HID, true><<<GEMMB, 256, 0, stream>>>(
            nullptr, h1h, ssg[g], rowg[g], Ws2[g], Wn2[g], partG[g], nullptr);
    }

    reduce1_kernel<<<RBLK, 256, 0, stream>>>(part0, part1, p2);
    final_kernel<<<1, 256, 0, stream>>>(p2, Wlin[0], Wlin[1], (float*)d_out);
}

// Round 8
// 880.145 us; speedup vs baseline: 1.0197x; 1.0068x over previous
//
#include <hip/hip_runtime.h>
#include <hip/hip_fp16.h>

#define NN 100000
#define NE 1600000
#define IND 64
#define HID 128
#define NCLS 16
#define GEMMB (NN / 16)   // 6250
#define RBLK 50
#define BK 98             // buckets (1024 nodes each)
#define BW 1024           // nodes per bucket
#define EPB 2048          // edges per block in bucket hist/place
#define NBG ((NE + EPB - 1) / EPB)   // 782 blocks per graph

// ---------------------------------------------------------------------------
// type-pun helpers
__device__ __forceinline__ __half2 as_h2(unsigned u) {
    union { unsigned u; __half2 h; } c; c.u = u; return c.h;
}
__device__ __forceinline__ unsigned as_u32(__half2 h) {
    union { unsigned u; __half2 h; } c; c.h = h; return c.u;
}

// ---------------------------------------------------------------------------
// fp32 -> f16 table conversion (8 elems / thread)
__global__ void conv16_kernel(const float4* __restrict__ x, uint4* __restrict__ o, int n8) {
    int i = blockIdx.x * blockDim.x + threadIdx.x;
    if (i >= n8) return;
    float4 a = x[2 * i], b = x[2 * i + 1];
    uint4 w;
    w.x = as_u32(__floats2half2_rn(a.x, a.y));
    w.y = as_u32(__floats2half2_rn(a.z, a.w));
    w.z = as_u32(__floats2half2_rn(b.x, b.y));
    w.w = as_u32(__floats2half2_rn(b.z, b.w));
    o[i] = w;
}

// ---------------------------------------------------------------------------
// bucket histogram (both graphs)
__global__ void bucket_hist(const int* __restrict__ d0, const int* __restrict__ d1,
                            int* __restrict__ bcnt) {
    __shared__ int h[BK];
    const int bi = blockIdx.x;
    const int g = bi >= NBG;
    const int* dst = g ? d1 : d0;
    const int base = (g ? bi - NBG : bi) * EPB;
    for (int i = threadIdx.x; i < BK; i += 256) h[i] = 0;
    __syncthreads();
    for (int j = 0; j < EPB; j += 256) {
        int e = base + j + threadIdx.x;
        if (e < NE) atomicAdd(&h[dst[e] >> 10], 1);
    }
    __syncthreads();
    for (int i = threadIdx.x; i < BK; i += 256)
        if (h[i]) atomicAdd(&bcnt[g * BK + i], h[i]);
}

// ---------------------------------------------------------------------------
__global__ void bucket_scan(const int* __restrict__ bcnt, int* __restrict__ bbase,
                            int* __restrict__ bcur) {
    int t = threadIdx.x;
    if (t < 2) {
        int run = 0;
        for (int i = 0; i < BK; i++) {
            bbase[t * (BK + 1) + i] = run;
            bcur[t * BK + i] = run;
            run += bcnt[t * BK + i];
        }
        bbase[t * (BK + 1) + BK] = run;
    }
}

// ---------------------------------------------------------------------------
// partition edges into bucket regions: src | (dst&1023)<<17
__global__ void bucket_place(const int* __restrict__ s0, const int* __restrict__ d0,
                             const int* __restrict__ s1, const int* __restrict__ d1,
                             int* __restrict__ bcur,
                             unsigned* __restrict__ p0, unsigned* __restrict__ p1) {
    __shared__ int h[BK], hb[BK];
    const int bi = blockIdx.x;
    const int g = bi >= NBG;
    const int* src = g ? s1 : s0;
    const int* dst = g ? d1 : d0;
    unsigned* pairs = g ? p1 : p0;
    const int base = (g ? bi - NBG : bi) * EPB;
    for (int i = threadIdx.x; i < BK; i += 256) h[i] = 0;
    __syncthreads();
    for (int j = 0; j < EPB; j += 256) {
        int e = base + j + threadIdx.x;
        if (e < NE) atomicAdd(&h[dst[e] >> 10], 1);
    }
    __syncthreads();
    for (int i = threadIdx.x; i < BK; i += 256) {
        hb[i] = h[i] ? atomicAdd(&bcur[g * BK + i], h[i]) : 0;
        h[i] = 0;
    }
    __syncthreads();
    for (int j = 0; j < EPB; j += 256) {
        int e = base + j + threadIdx.x;
        if (e < NE) {
            int d = dst[e];
            int b = d >> 10;
            int slot = atomicAdd(&h[b], 1);
            pairs[hb[b] + slot] = (unsigned)src[e] | ((unsigned)(d & 1023) << 17);
        }
    }
}

// ---------------------------------------------------------------------------
// one block per bucket: LDS hist + scan, write rowend + ssrc
__global__ __launch_bounds__(256) void bucket_final(
    const unsigned* __restrict__ p0, const unsigned* __restrict__ p1,
    const int* __restrict__ bbase,
    int* __restrict__ row0, int* __restrict__ row1,
    int* __restrict__ ss0, int* __restrict__ ss1) {
    __shared__ int cnt[BW];
    __shared__ int ex[BW];
    __shared__ int aux[256];
    const int bi = blockIdx.x;
    const int g = bi >= BK;
    const int b = g ? bi - BK : bi;
    const unsigned* pairs = g ? p1 : p0;
    int* rowend = g ? row1 : row0;
    int* ssrc = g ? ss1 : ss0;
    const int ebase = bbase[g * (BK + 1) + b];
    const int eend = bbase[g * (BK + 1) + b + 1];
    const int tid = threadIdx.x;

    for (int i = tid; i < BW; i += 256) cnt[i] = 0;
    __syncthreads();
    for (int e = ebase + tid; e < eend; e += 256)
        atomicAdd(&cnt[pairs[e] >> 17], 1);
    __syncthreads();

    int c0 = cnt[4 * tid], c1 = cnt[4 * tid + 1], c2 = cnt[4 * tid + 2], c3 = cnt[4 * tid + 3];
    aux[tid] = c0 + c1 + c2 + c3;
    __syncthreads();
    for (int off = 1; off < 256; off <<= 1) {
        int v = (tid >= off) ? aux[tid - off] : 0;
        __syncthreads();
        aux[tid] += v;
        __syncthreads();
    }
    int excl = tid ? aux[tid - 1] : 0;
    ex[4 * tid] = excl;
    ex[4 * tid + 1] = excl + c0;
    ex[4 * tid + 2] = excl + c0 + c1;
    ex[4 * tid + 3] = excl + c0 + c1 + c2;

    const int nodebase = b * BW + 4 * tid;
    if (nodebase + 0 < NN) rowend[nodebase + 0] = ebase + excl + c0;
    if (nodebase + 1 < NN) rowend[nodebase + 1] = ebase + excl + c0 + c1;
    if (nodebase + 2 < NN) rowend[nodebase + 2] = ebase + excl + c0 + c1 + c2;
    if (nodebase + 3 < NN) rowend[nodebase + 3] = ebase + excl + c0 + c1 + c2 + c3;
    __syncthreads();

    for (int e = ebase + tid; e < eend; e += 256) {
        unsigned pk = pairs[e];
        int dl = pk >> 17;
        int pos = ebase + atomicAdd(&ex[dl], 1);
        ssrc[pos] = (int)(pk & 0x1FFFFu);
    }
}

// ---------------------------------------------------------------------------
__device__ __forceinline__ void hacc4(__half2* hacc, uint4 v) {
    hacc[0] = __hadd2(hacc[0], as_h2(v.x));
    hacc[1] = __hadd2(hacc[1], as_h2(v.y));
    hacc[2] = __hadd2(hacc[2], as_h2(v.z));
    hacc[3] = __hadd2(hacc[3], as_h2(v.w));
}

// ---------------------------------------------------------------------------
// Fused SAGE layer. f16 gather tables; depth-4 software-pipelined gather
// (rotating register buffer; launch_bounds(256,4) gives the 128-VGPR headroom
// the pipeline needs — at bare launch_bounds(256) the allocator picked 32
// VGPRs and serialized every load).
template<int KS, bool REDUCE>
__global__ __launch_bounds__(256, 4) void sage_fused(
    const float* __restrict__ xf, const uint4* __restrict__ x16,
    const int* __restrict__ ssrc, const int* __restrict__ rowend,
    const float* __restrict__ Ws, const float* __restrict__ Wn,
    float* __restrict__ outR, unsigned* __restrict__ outH) {
    __shared__ float xms[16][2 * KS + 4];
    __shared__ float part[4][128];

    const int tid = threadIdx.x;
    const int n0 = blockIdx.x * 16;
    const int RW = KS / 8;  // uint4 per f16 row

    // ---- self staging ----
    {
        int node = tid / 16, c = tid % 16;
        if constexpr (KS == IND) {
            float4 v = ((const float4*)xf)[(size_t)(n0 + node) * 16 + c];
            *(float4*)&xms[node][c * 4] = v;
        } else {
            uint4 u = x16[(size_t)(n0 + node) * RW + c];
            float2 f0 = __half22float2(as_h2(u.x));
            float2 f1 = __half22float2(as_h2(u.y));
            float2 f2 = __half22float2(as_h2(u.z));
            float2 f3 = __half22float2(as_h2(u.w));
            *(float4*)&xms[node][c * 8] = make_float4(f0.x, f0.y, f1.x, f1.y);
            *(float4*)&xms[node][c * 8 + 4] = make_float4(f2.x, f2.y, f3.x, f3.y);
        }
    }

    // ---- neighbor mean aggregation ----
    {
        const int nb = tid >> 4;
        const int n = n0 + nb;
        const int start = (n == 0) ? 0 : rowend[n - 1];
        const int end = rowend[n];
        __half2 hacc[4];
#pragma unroll
        for (int j = 0; j < 4; j++) hacc[j] = __float2half2_rn(0.0f);

        if constexpr (KS == HID) {
            // 16 lanes/node, lane owns 16 B of the 256 B row; single chain,
            // depth-4 rotating prefetch.
            const int l = tid & 15;
            const uint4* base = x16 + l;
            int e = start;
            int rem = (end - start) & 3;
            for (; rem > 0; rem--, e++) hacc4(hacc, base[(size_t)ssrc[e] * 16]);
            if (e < end) {
                uint4 v0 = base[(size_t)ssrc[e + 0] * 16];
                uint4 v1 = base[(size_t)ssrc[e + 1] * 16];
                uint4 v2 = base[(size_t)ssrc[e + 2] * 16];
                uint4 v3 = base[(size_t)ssrc[e + 3] * 16];
                e += 4;
                for (; e < end; e += 4) {
                    int i0 = ssrc[e + 0], i1 = ssrc[e + 1];
                    int i2 = ssrc[e + 2], i3 = ssrc[e + 3];
                    uint4 p0 = base[(size_t)i0 * 16];
                    uint4 p1 = base[(size_t)i1 * 16];
                    uint4 p2 = base[(size_t)i2 * 16];
                    uint4 p3 = base[(size_t)i3 * 16];
                    hacc4(hacc, v0); hacc4(hacc, v1);
                    hacc4(hacc, v2); hacc4(hacc, v3);
                    v0 = p0; v1 = p1; v2 = p2; v3 = p3;
                }
                hacc4(hacc, v0); hacc4(hacc, v1);
                hacc4(hacc, v2); hacc4(hacc, v3);
            }
            float iv = 1.0f / fmaxf((float)(end - start), 1.0f);
            float2 f0 = __half22float2(hacc[0]);
            float2 f1 = __half22float2(hacc[1]);
            float2 f2 = __half22float2(hacc[2]);
            float2 f3 = __half22float2(hacc[3]);
            *(float4*)&xms[nb][KS + l * 8] =
                make_float4(f0.x * iv, f0.y * iv, f1.x * iv, f1.y * iv);
            *(float4*)&xms[nb][KS + l * 8 + 4] =
                make_float4(f2.x * iv, f2.y * iv, f3.x * iv, f3.y * iv);
        } else {
            // 8 lanes/node x 2 chains (even/odd edges); lane owns 16 B of the
            // 128 B row; depth-4 rotating prefetch per chain; shfl_xor(8) merge.
            const int sub = tid & 15;
            const int l = sub & 7;
            const int h = sub >> 3;
            const uint4* base = x16 + l;
            int e = start + h;
            int d = end - e;                 // remaining edges in stride-2 chain
            int cnt = (d > 0) ? ((d + 1) >> 1) : 0;
            int rem = cnt & 3;
            for (; rem > 0; rem--, e += 2) hacc4(hacc, base[(size_t)ssrc[e] * 8]);
            if (cnt >= 4) {
                uint4 v0 = base[(size_t)ssrc[e + 0] * 8];
                uint4 v1 = base[(size_t)ssrc[e + 2] * 8];
                uint4 v2 = base[(size_t)ssrc[e + 4] * 8];
                uint4 v3 = base[(size_t)ssrc[e + 6] * 8];
                e += 8;
                for (; e < end; e += 8) {
                    int i0 = ssrc[e + 0], i1 = ssrc[e + 2];
                    int i2 = ssrc[e + 4], i3 = ssrc[e + 6];
                    uint4 p0 = base[(size_t)i0 * 8];
                    uint4 p1 = base[(size_t)i1 * 8];
                    uint4 p2 = base[(size_t)i2 * 8];
                    uint4 p3 = base[(size_t)i3 * 8];
                    hacc4(hacc, v0); hacc4(hacc, v1);
                    hacc4(hacc, v2); hacc4(hacc, v3);
                    v0 = p0; v1 = p1; v2 = p2; v3 = p3;
                }
                hacc4(hacc, v0); hacc4(hacc, v1);
                hacc4(hacc, v2); hacc4(hacc, v3);
            }
#pragma unroll
            for (int j = 0; j < 4; j++) {
                int t = __shfl_xor((int)as_u32(hacc[j]), 8);
                hacc[j] = __hadd2(hacc[j], as_h2((unsigned)t));
            }
            if (h == 0) {
                float iv = 1.0f / fmaxf((float)(end - start), 1.0f);
                float2 f0 = __half22float2(hacc[0]);
                float2 f1 = __half22float2(hacc[1]);
                float2 f2 = __half22float2(hacc[2]);
                float2 f3 = __half22float2(hacc[3]);
                *(float4*)&xms[nb][KS + l * 8] =
                    make_float4(f0.x * iv, f0.y * iv, f1.x * iv, f1.y * iv);
                *(float4*)&xms[nb][KS + l * 8 + 4] =
                    make_float4(f2.x * iv, f2.y * iv, f3.x * iv, f3.y * iv);
            }
        }
    }
    __syncthreads();

    // ---- GEMM: out = relu([xs|ms] @ [Ws;Wn]) ----
    const int p = tid % 64;
    const int q = tid / 64;
    float a00 = 0, a01 = 0, a10 = 0, a11 = 0, a20 = 0, a21 = 0, a30 = 0, a31 = 0;

#pragma unroll
    for (int seg = 0; seg < 2; seg++) {
        const float* __restrict__ W = seg ? Wn : Ws;
        const int koff = seg * KS;
#pragma unroll 2
        for (int k = 0; k < KS; k += 4) {
            const float* Wk = W + (size_t)k * HID + 2 * p;
            float2 w0 = *(const float2*)(Wk);
            float2 w1 = *(const float2*)(Wk + HID);
            float2 w2 = *(const float2*)(Wk + 2 * HID);
            float2 w3 = *(const float2*)(Wk + 3 * HID);
            float4 v0 = *(const float4*)&xms[4 * q + 0][koff + k];
            float4 v1 = *(const float4*)&xms[4 * q + 1][koff + k];
            float4 v2 = *(const float4*)&xms[4 * q + 2][koff + k];
            float4 v3 = *(const float4*)&xms[4 * q + 3][koff + k];
            a00 += v0.x * w0.x + v0.y * w1.x + v0.z * w2.x + v0.w * w3.x;
            a01 += v0.x * w0.y + v0.y * w1.y + v0.z * w2.y + v0.w * w3.y;
            a10 += v1.x * w0.x + v1.y * w1.x + v1.z * w2.x + v1.w * w3.x;
            a11 += v1.x * w0.y + v1.y * w1.y + v1.z * w2.y + v1.w * w3.y;
            a20 += v2.x * w0.x + v2.y * w1.x + v2.z * w2.x + v2.w * w3.x;
            a21 += v2.x * w0.y + v2.y * w1.y + v2.z * w2.y + v2.w * w3.y;
            a30 += v3.x * w0.x + v3.y * w1.x + v3.z * w2.x + v3.w * w3.x;
            a31 += v3.x * w0.y + v3.y * w1.y + v3.z * w2.y + v3.w * w3.y;
        }
    }

    if constexpr (!REDUCE) {
        float r0, r1;
        r0 = fmaxf(a00, 0.f); r1 = fmaxf(a01, 0.f);
        outH[(size_t)(n0 + 4 * q + 0) * 64 + p] = as_u32(__floats2half2_rn(r0, r1));
        r0 = fmaxf(a10, 0.f); r1 = fmaxf(a11, 0.f);
        outH[(size_t)(n0 + 4 * q + 1) * 64 + p] = as_u32(__floats2half2_rn(r0, r1));
        r0 = fmaxf(a20, 0.f); r1 = fmaxf(a21, 0.f);
        outH[(size_t)(n0 + 4 * q + 2) * 64 + p] = as_u32(__floats2half2_rn(r0, r1));
        r0 = fmaxf(a30, 0.f); r1 = fmaxf(a31, 0.f);
        outH[(size_t)(n0 + 4 * q + 3) * 64 + p] = as_u32(__floats2half2_rn(r0, r1));
    } else {
        float s0 = fmaxf(a00, 0.f) + fmaxf(a10, 0.f) + fmaxf(a20, 0.f) + fmaxf(a30, 0.f);
        float s1 = fmaxf(a01, 0.f) + fmaxf(a11, 0.f) + fmaxf(a21, 0.f) + fmaxf(a31, 0.f);
        *(float2*)&part[q][2 * p] = make_float2(s0, s1);
        __syncthreads();
        if (tid < 128) {
            float s = part[0][tid] + part[1][tid] + part[2][tid] + part[3][tid];
            outR[(size_t)blockIdx.x * 128 + tid] = s;
        }
    }
}

// ---------------------------------------------------------------------------
__global__ void reduce1_kernel(const float* __restrict__ p0, const float* __restrict__ p1,
                               float* __restrict__ p2) {
    const int bb = blockIdx.x;
    const int tid = threadIdx.x;
    const int g = tid >> 7;
    const int col = tid & 127;
    const float* p = g ? p1 : p0;
    const int per = GEMMB / RBLK;
    float s = 0.0f;
    for (int r = 0; r < per; r++) s += p[(size_t)(bb * per + r) * 128 + col];
    p2[(size_t)bb * 256 + tid] = s;
}

__global__ void final_kernel(const float* __restrict__ p2,
                             const float* __restrict__ Wlin1,
                             const float* __restrict__ Wlin2,
                             float* __restrict__ out) {
    __shared__ float rep[2][HID];
    __shared__ float sg[32];
    const int tid = threadIdx.x;
    float s = 0.0f;
    for (int r = 0; r < RBLK; r++) s += p2[r * 256 + tid];
    rep[tid >> 7][tid & 127] = s * (1.0f / (float)NN);
    __syncthreads();
    if (tid < 32) {
        const int g = tid / 16;
        const int c = tid % 16;
        const float* W = g ? Wlin2 : Wlin1;
        float a = 0.0f;
        for (int k = 0; k < HID; k++) a += rep[g][k] * W[k * NCLS + c];
        sg[tid] = 1.0f / (1.0f + expf(-a));
    }
    __syncthreads();
    if (tid < 16) out[tid] = 0.5f * (sg[tid] + sg[16 + tid]);
}

// ---------------------------------------------------------------------------
extern "C" void kernel_launch(void* const* d_in, const int* in_sizes, int n_in,
                              void* d_out, int out_size, void* d_ws, size_t ws_size,
                              hipStream_t stream) {
    const float* feats = (const float*)d_in[0];
    const int* srcp[2] = {(const int*)d_in[1], (const int*)d_in[3]};
    const int* dstp[2] = {(const int*)d_in[2], (const int*)d_in[4]};
    const float* Ws1[2] = {(const float*)d_in[5], (const float*)d_in[10]};
    const float* Wn1[2] = {(const float*)d_in[6], (const float*)d_in[11]};
    const float* Ws2[2] = {(const float*)d_in[7], (const float*)d_in[12]};
    const float* Wn2[2] = {(const float*)d_in[8], (const float*)d_in[13]};
    const float* Wlin[2] = {(const float*)d_in[9], (const float*)d_in[14]};

    // workspace layout (~90 MB), 16B-aligned sections
    char* w = (char*)d_ws;
    uint4* fb16 = (uint4*)w;        w += (size_t)NN * IND * 2;      // feats f16
    uint4* h1h = (uint4*)w;         w += (size_t)NN * HID * 2;      // h1 f16
    float* part0 = (float*)w;       w += (size_t)GEMMB * 128 * 4;
    float* part1 = (float*)w;       w += (size_t)GEMMB * 128 * 4;
    float* p2 = (float*)w;          w += (size_t)RBLK * 256 * 4;
    unsigned* pr0 = (unsigned*)w;   w += (size_t)NE * 4;
    unsigned* pr1 = (unsigned*)w;   w += (size_t)NE * 4;
    int* ss0 = (int*)w;             w += (size_t)NE * 4;
    int* ss1 = (int*)w;             w += (size_t)NE * 4;
    int* row0 = (int*)w;            w += (size_t)NN * 4;
    int* row1 = (int*)w;            w += (size_t)NN * 4;
    int* bcnt = (int*)w;            w += 2 * BK * 4;
    int* bbase = (int*)w;           w += 2 * (BK + 1) * 4;
    int* bcur = (int*)w;            w += 2 * BK * 4;

    // feats -> f16 table
    conv16_kernel<<<(NN * IND / 8 + 255) / 256, 256, 0, stream>>>(
        (const float4*)feats, fb16, NN * IND / 8);

    // bucketed CSR build, both graphs
    (void)hipMemsetAsync(bcnt, 0, 2 * BK * 4, stream);
    bucket_hist<<<2 * NBG, 256, 0, stream>>>(dstp[0], dstp[1], bcnt);
    bucket_scan<<<1, 64, 0, stream>>>(bcnt, bbase, bcur);
    bucket_place<<<2 * NBG, 256, 0, stream>>>(srcp[0], dstp[0], srcp[1], dstp[1],
                                              bcur, pr0, pr1);
    bucket_final<<<2 * BK, 256, 0, stream>>>(pr0, pr1, bbase, row0, row1, ss0, ss1);

    const int* ssg[2] = {ss0, ss1};
    const int* rowg[2] = {row0, row1};
    float* partG[2] = {part0, part1};

    for (int g = 0; g < 2; g++) {
        sage_fused<IND, false><<<GEMMB, 256, 0, stream>>>(
            feats, fb16, ssg[g], rowg[g], Ws1[g], Wn1[g], nullptr, (unsigned*)h1h);
        sage_fused<HID, true><<<GEMMB, 256, 0, stream>>>(
            nullptr, h1h, ssg[g], rowg[g], Ws2[g], Wn2[g], partG[g], nullptr);
    }

    reduce1_kernel<<<RBLK, 256, 0, stream>>>(part0, part1, p2);
    final_kernel<<<1, 256, 0, stream>>>(p2, Wlin[0], Wlin[1], (float*)d_out);
}